// Round 20
// baseline (1691.693 us; speedup 1.0000x reference)
//
#include <hip/hip_runtime.h>
#include <math.h>

#define Bz 32
#define Tz 512
#define Dz 1024
#define Pz 512
#define Ez 256
#define KC 14
#define NHz 4
#define Lz 2
#define FFz 2048
#define TOPKz 7
#define EPSz 1e-5f
#define BT (Bz*Tz)

typedef unsigned short ushort_t;
typedef __attribute__((ext_vector_type(8))) short short8;
typedef __attribute__((ext_vector_type(4))) float f32x4;

__device__ __forceinline__ ushort_t f2bf(float f) {
    union { float f; unsigned int u; } x; x.f = f;
    unsigned int r = x.u + 0x7fffu + ((x.u >> 16) & 1u);   // RNE (finite inputs)
    return (ushort_t)(r >> 16);
}
__device__ __forceinline__ float bf2f(ushort_t h) {
    union { unsigned int u; float f; } x; x.u = ((unsigned int)h) << 16; return x.f;
}

#define GLDS(gp, lp) __builtin_amdgcn_global_load_lds( \
    (const __attribute__((address_space(1))) unsigned int*)(gp), \
    (__attribute__((address_space(3))) unsigned int*)(lp), 16, 0, 0)

// ---------------- 128x128 bf16 MFMA GEMM (m97) + serpentine XCD swizzle + staged C-write -------
__global__ __launch_bounds__(256) void mgemm_k(
    const ushort_t* __restrict__ A, int lda,
    const ushort_t* __restrict__ Wt,
    const float* __restrict__ bias,
    float* __restrict__ Cf, ushort_t* __restrict__ Ch, int ldc,
    int Kd, int epi,
    const float* __restrict__ bng, const float* __restrict__ bnb,
    const float* __restrict__ bnm, const float* __restrict__ bnv)
{
    __shared__ __align__(16) ushort_t smem[128 * 136];   // As|Bs (16KB) in loop; C-stage after
    ushort_t* As = smem;
    ushort_t* Bs = smem + 128 * 32;
    const int tid = threadIdx.x;
    const int lane = tid & 63, wid0 = tid >> 6;
    const int gx = gridDim.x;
    const int f = blockIdx.y * gx + blockIdx.x;
    const int chunk = f & 7;
    const int local = f >> 3;                             // 0 .. nwg/8-1
    const int rowsPerChunk = gridDim.y >> 3;              // 16 here
    const int bandSz = 4 * gx;
    const int band = local / bandSz;
    const int rem  = local - band * bandSz;
    const int row0 = (chunk * rowsPerChunk + band * 4 + (rem & 3)) * 128;
    const int col0 = (rem >> 2) * 128;
    const int wrow = (wid0 >> 1) * 64, wcol = (wid0 & 1) * 64;
    const int srow = (lane >> 2);
    const int skoff = (lane & 3) * 8;

    f32x4 acc[4][4];
    const f32x4 zr = {0.f, 0.f, 0.f, 0.f};
    #pragma unroll
    for (int m = 0; m < 4; m++)
        #pragma unroll
        for (int n = 0; n < 4; n++) acc[m][n] = zr;

    for (int k0 = 0; k0 < Kd; k0 += 32) {
        #pragma unroll
        for (int j = 0; j < 2; j++) {
            const int r = wid0 * 32 + j * 16;
            GLDS(A + (size_t)(row0 + r + srow) * lda + k0 + skoff, As + r * 32);
            GLDS(Wt + (size_t)(col0 + r + srow) * Kd + k0 + skoff, Bs + r * 32);
        }
        __syncthreads();
        short8 af[4], bf[4];
        #pragma unroll
        for (int m = 0; m < 4; m++)
            af[m] = *(const short8*)(As + (wrow + m * 16 + (lane & 15)) * 32 + (lane >> 4) * 8);
        #pragma unroll
        for (int n = 0; n < 4; n++)
            bf[n] = *(const short8*)(Bs + (wcol + n * 16 + (lane & 15)) * 32 + (lane >> 4) * 8);
        #pragma unroll
        for (int m = 0; m < 4; m++)
            #pragma unroll
            for (int n = 0; n < 4; n++)
                acc[m][n] = __builtin_amdgcn_mfma_f32_16x16x32_bf16(af[m], bf[n], acc[m][n], 0, 0, 0);
        __syncthreads();
    }

    // ---- epilogue: bias/BN/relu; fp32 scalar (full sectors); bf16 via LDS stage ----
    #pragma unroll
    for (int n = 0; n < 4; n++) {
        const int lcol = wcol + n * 16 + (lane & 15);
        const int ccol = col0 + lcol;
        const float bb = bias[ccol];
        float bsc = 1.f, bsh = 0.f;
        if (epi == 2) {
            bsc = rsqrtf(bnv[ccol] + EPSz) * bng[ccol];
            bsh = bnb[ccol] - bnm[ccol] * bsc;
        }
        #pragma unroll
        for (int m = 0; m < 4; m++) {
            #pragma unroll
            for (int r = 0; r < 4; r++) {
                const int lrow = wrow + m * 16 + (lane >> 4) * 4 + r;
                float y = acc[m][n][r] + bb;
                if (epi == 2) y = y * bsc + bsh;
                if (epi >= 1) y = fmaxf(y, 0.f);
                if (Cf) Cf[(size_t)(row0 + lrow) * ldc + ccol] = y;
                if (Ch) smem[lrow * 136 + lcol] = f2bf(y);
            }
        }
    }
    if (Ch) {
        __syncthreads();
        #pragma unroll
        for (int i = 0; i < 8; i++) {
            const int row = (tid >> 4) + i * 16;
            const int seg = (tid & 15) * 8;
            *(uint4*)(Ch + (size_t)(row0 + row) * ldc + col0 + seg) =
                *(const uint4*)(smem + row * 136 + seg);
        }
    }
}

// ---------------- fused flash attention: S=QK^T -> softmax -> O=PV, P kept in LDS --------------
__global__ __launch_bounds__(1024) void flash_k(
    ushort_t* __restrict__ qkvb, const ushort_t* __restrict__ Vt)
{
    __shared__ __align__(16) ushort_t Plds[128 * 512];   // 128KB; QK staging + O staging overlap
    __shared__ __align__(16) ushort_t Bs2[256 * 32];     // 16KB (PV V^T tiles)
    __shared__ float red[128][4];                        // 2KB
    ushort_t* As = Plds;              // 8KB  (QK phase)
    ushort_t* Bs = Plds + 128 * 32;   // 32KB (QK phase)

    const int z = blockIdx.y, bl = z >> 2, hh = z & 3;
    const int row0 = blockIdx.x * 128;
    ushort_t* Qs = qkvb + (size_t)bl * 512 * 3072 + hh * 256;          // Q (and O dest)
    const ushort_t* Ks = qkvb + (size_t)bl * 512 * 3072 + 1024 + hh * 256;
    const ushort_t* V = Vt + (size_t)z * 256 * 512;
    const int tid = threadIdx.x, lane = tid & 63, w = tid >> 6;
    const int wr = w >> 2, wc = w & 3;                   // 4 x 4

    // ---- phase 1: S = Q K^T ----
    f32x4 acc[2][8];
    const f32x4 zr = {0.f, 0.f, 0.f, 0.f};
    #pragma unroll
    for (int m = 0; m < 2; m++)
        #pragma unroll
        for (int n = 0; n < 8; n++) acc[m][n] = zr;

    for (int d0 = 0; d0 < 256; d0 += 32) {
        if (w < 8) {
            const int rbu = w * 16;
            const int row = rbu + (lane >> 2);
            GLDS(Qs + (size_t)(row0 + row) * 3072 + d0 + (lane & 3) * 8, As + rbu * 32);
        } else {
            #pragma unroll
            for (int i = 0; i < 4; i++) {
                const int rbu = (w - 8) * 64 + i * 16;
                const int row = rbu + (lane >> 2);
                GLDS(Ks + (size_t)row * 3072 + d0 + (lane & 3) * 8, Bs + rbu * 32);
            }
        }
        __syncthreads();
        short8 af[2];
        #pragma unroll
        for (int m = 0; m < 2; m++)
            af[m] = *(const short8*)(As + (wr * 32 + m * 16 + (lane & 15)) * 32 + (lane >> 4) * 8);
        #pragma unroll
        for (int n = 0; n < 8; n++) {
            const short8 bfv = *(const short8*)(Bs + (wc * 128 + n * 16 + (lane & 15)) * 32 + (lane >> 4) * 8);
            #pragma unroll
            for (int m = 0; m < 2; m++)
                acc[m][n] = __builtin_amdgcn_mfma_f32_16x16x32_bf16(af[m], bfv, acc[m][n], 0, 0, 0);
        }
        __syncthreads();
    }

    // ---- phase 2: softmax (scale 1/16) ----
    #pragma unroll
    for (int m = 0; m < 2; m++)
        #pragma unroll
        for (int n = 0; n < 8; n++) acc[m][n] *= 0.0625f;

    float rmx[2][4], rinv[2][4];
    #pragma unroll
    for (int m = 0; m < 2; m++)
        #pragma unroll
        for (int r = 0; r < 4; r++) {
            float mx = acc[m][0][r];
            #pragma unroll
            for (int n = 1; n < 8; n++) mx = fmaxf(mx, acc[m][n][r]);
            mx = fmaxf(mx, __shfl_xor(mx, 1));
            mx = fmaxf(mx, __shfl_xor(mx, 2));
            mx = fmaxf(mx, __shfl_xor(mx, 4));
            mx = fmaxf(mx, __shfl_xor(mx, 8));
            if ((lane & 15) == 0) red[wr * 32 + m * 16 + (lane >> 4) * 4 + r][wc] = mx;
        }
    __syncthreads();
    #pragma unroll
    for (int m = 0; m < 2; m++)
        #pragma unroll
        for (int r = 0; r < 4; r++) {
            const int rw = wr * 32 + m * 16 + (lane >> 4) * 4 + r;
            rmx[m][r] = fmaxf(fmaxf(red[rw][0], red[rw][1]), fmaxf(red[rw][2], red[rw][3]));
        }
    __syncthreads();
    #pragma unroll
    for (int m = 0; m < 2; m++)
        #pragma unroll
        for (int r = 0; r < 4; r++) {
            float s = 0.f;
            #pragma unroll
            for (int n = 0; n < 8; n++) {
                const float e = expf(acc[m][n][r] - rmx[m][r]);
                acc[m][n][r] = e; s += e;
            }
            s += __shfl_xor(s, 1); s += __shfl_xor(s, 2);
            s += __shfl_xor(s, 4); s += __shfl_xor(s, 8);
            if ((lane & 15) == 0) red[wr * 32 + m * 16 + (lane >> 4) * 4 + r][wc] = s;
        }
    __syncthreads();
    #pragma unroll
    for (int m = 0; m < 2; m++)
        #pragma unroll
        for (int r = 0; r < 4; r++) {
            const int rw = wr * 32 + m * 16 + (lane >> 4) * 4 + r;
            rinv[m][r] = 1.f / (red[rw][0] + red[rw][1] + red[rw][2] + red[rw][3]);
        }
    __syncthreads();

    // write normalized P (bf16) into Plds, XOR-swizzled: byte ^= (row&7)<<4
    char* Pc = (char*)Plds;
    #pragma unroll
    for (int m = 0; m < 2; m++)
        #pragma unroll
        for (int r = 0; r < 4; r++) {
            const int rw = wr * 32 + m * 16 + (lane >> 4) * 4 + r;
            const int rx = (rw & 7) << 4;
            #pragma unroll
            for (int n = 0; n < 8; n++) {
                const int col = wc * 128 + n * 16 + (lane & 15);
                *(ushort_t*)(Pc + (((rw * 512 + col) * 2) ^ rx)) = f2bf(acc[m][n][r] * rinv[m][r]);
            }
        }
    __syncthreads();

    // ---- phase 3: O = P @ Vt^T ----
    f32x4 acc2[2][4];
    #pragma unroll
    for (int m = 0; m < 2; m++)
        #pragma unroll
        for (int n = 0; n < 4; n++) acc2[m][n] = zr;

    for (int k0 = 0; k0 < 512; k0 += 32) {
        {
            const int rbu = w * 16;
            const int row = rbu + (lane >> 2);
            GLDS(V + (size_t)row * 512 + k0 + (lane & 3) * 8, Bs2 + rbu * 32);
        }
        __syncthreads();
        short8 af2[2];
        #pragma unroll
        for (int m = 0; m < 2; m++) {
            const int rw = wr * 32 + m * 16 + (lane & 15);
            const int rx = (rw & 7) << 4;
            af2[m] = *(const short8*)(Pc + (((rw * 512 + k0 + (lane >> 4) * 8) * 2) ^ rx));
        }
        #pragma unroll
        for (int n = 0; n < 4; n++) {
            const short8 bfv = *(const short8*)(Bs2 + (wc * 64 + n * 16 + (lane & 15)) * 32 + (lane >> 4) * 8);
            #pragma unroll
            for (int m = 0; m < 2; m++)
                acc2[m][n] = __builtin_amdgcn_mfma_f32_16x16x32_bf16(af2[m], bfv, acc2[m][n], 0, 0, 0);
        }
        __syncthreads();
    }

    // ---- O epilogue: stage bf16 [128][256] into Plds (now free), coalesced uint4 write ----
    #pragma unroll
    for (int n = 0; n < 4; n++) {
        const int ccol = wc * 64 + n * 16 + (lane & 15);
        #pragma unroll
        for (int m = 0; m < 2; m++)
            #pragma unroll
            for (int r = 0; r < 4; r++) {
                const int lrow = wr * 32 + m * 16 + (lane >> 4) * 4 + r;
                Plds[lrow * 256 + ccol] = f2bf(acc2[m][n][r]);
            }
    }
    __syncthreads();
    #pragma unroll
    for (int i = 0; i < 4; i++) {
        const int row = (tid >> 5) + i * 32;
        const int seg = (tid & 31) * 8;
        *(uint4*)(Qs + (size_t)(row0 + row) * 3072 + seg) = *(const uint4*)(Plds + row * 256 + seg);
    }
}

// ------------- z-batched bf16 transpose: V[kv][d] (qkvb v-slots) -> Vt[d][kv] ------------------
__global__ __launch_bounds__(256) void vtb_k(
    const ushort_t* __restrict__ qkvb, ushort_t* __restrict__ Vt)
{
    const int z = blockIdx.z, bl = z >> 2, hh = z & 3;
    const ushort_t* src = qkvb + (size_t)bl * 512 * 3072 + 2048 + hh * 256;
    ushort_t* dst = Vt + (size_t)z * 256 * 512;
    __shared__ ushort_t t[32][33];
    const int tx = threadIdx.x & 31, ty = threadIdx.x >> 5;
    const int gx = blockIdx.x * 32;   // d
    const int gy = blockIdx.y * 32;   // kv
    #pragma unroll
    for (int i = 0; i < 4; i++) {
        const int row = ty + i * 8;
        t[row][tx] = src[(size_t)(gy + row) * 3072 + gx + tx];
    }
    __syncthreads();
    #pragma unroll
    for (int i = 0; i < 4; i++) {
        const int nr = ty + i * 8;
        dst[(size_t)(gx + nr) * 512 + gy + tx] = t[tx][nr];
    }
}

// ------------- merged weight transpose+cast: 13 jobs, one launch -------------------------------
struct WtJobs {
    const float* src[13];
    ushort_t*    dst[13];
    int ld[13];
    int Kd[13];
    int nx[13];
    int base[14];
};

__global__ __launch_bounds__(256) void wtall_k(WtJobs J)
{
    const int bid = blockIdx.x;
    int j = 0;
    #pragma unroll
    for (int i = 0; i < 12; i++) if (bid >= J.base[i + 1]) j = i + 1;
    const int local = bid - J.base[j];
    const int bx = local % J.nx[j], by = local / J.nx[j];
    const float* src = J.src[j];
    ushort_t* dst = J.dst[j];
    const int ld = J.ld[j], Kd = J.Kd[j];

    __shared__ float t[32][33];
    const int tx = threadIdx.x & 31, ty = threadIdx.x >> 5;
    const int gx = bx * 32;
    const int gy = by * 32;
    #pragma unroll
    for (int i = 0; i < 4; i++) {
        const int row = ty + i * 8;
        t[row][tx] = src[(size_t)(gy + row) * ld + gx + tx];
    }
    __syncthreads();
    #pragma unroll
    for (int i = 0; i < 4; i++) {
        const int nr = ty + i * 8;
        dst[(size_t)(gx + nr) * Kd + gy + tx] = f2bf(t[tx][nr]);
    }
}

// ------------- fused shift-predictor + TSM shift (bf16 out) ------------------------------------
__global__ __launch_bounds__(256) void predshift_k(
    const float* __restrict__ x, const float* __restrict__ pred_w,
    const float* __restrict__ pred_b, ushort_t* __restrict__ hb)
{
    const int row = blockIdx.x, tid = threadIdx.x;
    const size_t base = (size_t)row * Dz;
    float s = 0.f;
    #pragma unroll
    for (int i = 0; i < 4; i++) {
        int c = tid + i * 256;
        s += x[base + c] * pred_w[c];
    }
    __shared__ float red[256];
    __shared__ int sns;
    red[tid] = s; __syncthreads();
    for (int off = 128; off > 0; off >>= 1) {
        if (tid < off) red[tid] += red[tid + off];
        __syncthreads();
    }
    if (tid == 0) {
        float sg = 1.f / (1.f + expf(-(red[0] + pred_b[0])));
        sns = (int)(sg * (float)(Dz / 2));
    }
    __syncthreads();
    const int sn = sns;
    const int t = row & (Tz - 1);
    #pragma unroll
    for (int i = 0; i < 4; i++) {
        const int c = tid + i * 256;
        const size_t idx = base + c;
        float v;
        if (c < sn)          v = (t > 0)      ? x[idx - Dz] : 0.f;
        else if (c < 2 * sn) v = (t < Tz - 1) ? x[idx + Dz] : 0.f;
        else                 v = x[idx];
        hb[idx] = f2bf(v);
    }
}

// ------------- hb = bf16(LN(hb + r)) — bf16 residual stream ------------------------------------
__global__ __launch_bounds__(256) void addlnb_k(
    ushort_t* __restrict__ hb, const ushort_t* __restrict__ r,
    const float* __restrict__ g, const float* __restrict__ b)
{
    const int row = blockIdx.x, tid = threadIdx.x;
    const size_t base = (size_t)row * Dz;
    float x[4]; float s = 0.f, sq = 0.f;
    #pragma unroll
    for (int i = 0; i < 4; i++) {
        const int c = tid + i * 256;
        x[i] = bf2f(hb[base + c]) + bf2f(r[base + c]);
        s += x[i]; sq += x[i] * x[i];
    }
    __shared__ float rs[256], rq[256];
    rs[tid] = s; rq[tid] = sq; __syncthreads();
    for (int off = 128; off > 0; off >>= 1) {
        if (tid < off) { rs[tid] += rs[tid + off]; rq[tid] += rq[tid + off]; }
        __syncthreads();
    }
    float mean = rs[0] * (1.f / Dz);
    float var = rq[0] * (1.f / Dz) - mean * mean;
    float inv = rsqrtf(var + EPSz);
    #pragma unroll
    for (int i = 0; i < 4; i++) {
        int c = tid + i * 256;
        float y = (x[i] - mean) * inv * g[c] + b[c];
        hb[base + c] = f2bf(y);
    }
}

// ------------- rowdot: out[row] = dot(in[row,:512], w) + b -------------------------------------
__global__ __launch_bounds__(256) void rowdot_k(
    const float* __restrict__ in, const float* __restrict__ w,
    const float* __restrict__ bptr, float* __restrict__ outf)
{
    const int row = blockIdx.x, tid = threadIdx.x;
    const float* r = in + (size_t)row * Pz;
    float s = 0.f;
    #pragma unroll
    for (int c = tid; c < Pz; c += 256) s += r[c] * w[c];
    __shared__ float red[256];
    red[tid] = s; __syncthreads();
    for (int off = 128; off > 0; off >>= 1) {
        if (tid < off) red[tid] += red[tid + off];
        __syncthreads();
    }
    if (tid == 0) outf[row] = red[0] + bptr[0];
}

// ------------- fused tail: top-k -> agg -> classifier -> logits + cross-q (grid = Bc) ----------
__global__ __launch_bounds__(256) void tailcls_k(
    const float* __restrict__ scores, const float* __restrict__ shared_,
    const float* __restrict__ cc_w1, const float* __restrict__ cc_b1,
    const float* __restrict__ g2, const float* __restrict__ b2,
    const float* __restrict__ m2, const float* __restrict__ v2,
    const float* __restrict__ cc_w2, const float* __restrict__ cc_b2,
    const float* __restrict__ ce,
    const float* __restrict__ ca_wqkv, const float* __restrict__ ca_bqkv,
    float* __restrict__ logits_out, float* __restrict__ qx)
{
    const int b = blockIdx.x, tid = threadIdx.x;
    __shared__ float sv[Tz];
    __shared__ float rv[256]; __shared__ int ri[256];
    __shared__ int tki[TOPKz];
    __shared__ float ag[Pz], c1s[256], sm[16], cemb[256];

    sv[tid] = scores[b * Tz + tid];
    sv[tid + 256] = scores[b * Tz + tid + 256];
    __syncthreads();

    for (int it = 0; it < TOPKz; it++) {
        float v0 = sv[tid]; int i0 = tid;
        float v1 = sv[tid + 256];
        if (v1 > v0) { v0 = v1; i0 = tid + 256; }
        rv[tid] = v0; ri[tid] = i0; __syncthreads();
        for (int off = 128; off > 0; off >>= 1) {
            if (tid < off) {
                if (rv[tid + off] > rv[tid] ||
                    (rv[tid + off] == rv[tid] && ri[tid + off] < ri[tid])) {
                    rv[tid] = rv[tid + off]; ri[tid] = ri[tid + off];
                }
            }
            __syncthreads();
        }
        if (tid == 0) { tki[it] = ri[0]; sv[ri[0]] = -INFINITY; }
        __syncthreads();
    }

    const float* base = shared_ + (size_t)b * Tz * Pz;
    for (int p = tid; p < Pz; p += 256) {
        float s = 0.f;
        #pragma unroll
        for (int j = 0; j < TOPKz; j++) s += base[(size_t)tki[j] * Pz + p];
        ag[p] = s * (1.f / TOPKz);
    }
    __syncthreads();

    float s = 0.f;
    #pragma unroll 8
    for (int p = 0; p < Pz; p++) s += ag[p] * cc_w1[p * 256 + tid];
    s += cc_b1[tid];
    s = (s - m2[tid]) * rsqrtf(v2[tid] + EPSz) * g2[tid] + b2[tid];
    s = fmaxf(s, 0.f);
    c1s[tid] = s;
    __syncthreads();
    if (tid < KC) {
        float l = 0.f;
        #pragma unroll 8
        for (int e = 0; e < 256; e++) l += c1s[e] * cc_w2[e * KC + tid];
        l += cc_b2[tid];
        sm[tid] = l;
        logits_out[b * KC + tid] = l;
    }
    __syncthreads();
    if (tid == 0) {
        float mx = sm[0];
        for (int k = 1; k < KC; k++) mx = fmaxf(mx, sm[k]);
        float su = 0.f;
        for (int k = 0; k < KC; k++) { sm[k] = expf(sm[k] - mx); su += sm[k]; }
        float inv = 1.f / su;
        for (int k = 0; k < KC; k++) sm[k] *= inv;
    }
    __syncthreads();
    float cesum = 0.f;
    #pragma unroll
    for (int k = 0; k < KC; k++) cesum += sm[k] * ce[k * 256 + tid];
    cemb[tid] = cesum; __syncthreads();
    float q = 0.f;
    #pragma unroll 8
    for (int i = 0; i < 256; i++) q += cemb[i] * ca_wqkv[i * 768 + tid];
    qx[b * 256 + tid] = q + ca_bqkv[tid];
}

// ------------- cross-attention (Tq=1) on combined kv[R,512] + fused wo projection --------------
__global__ __launch_bounds__(256) void xattn_k(
    const float* __restrict__ qx, const float* __restrict__ kv,
    const float* __restrict__ ca_wo, const float* __restrict__ ca_bo,
    float* __restrict__ ctx2)
{
    const int b = blockIdx.x, tid = threadIdx.x;
    __shared__ float q4[256];
    __shared__ float sc[NHz][Tz];
    __shared__ float cx[256];
    q4[tid] = qx[b * 256 + tid];
    __syncthreads();
    for (int si = tid; si < NHz * Tz; si += 256) {
        int hh = si >> 9, t = si & (Tz - 1);
        const float* kr = kv + ((size_t)b * Tz + t) * 512 + hh * 64;
        const float* qr = q4 + hh * 64;
        float s = 0.f;
        #pragma unroll 8
        for (int d = 0; d < 64; d++) s += qr[d] * kr[d];
        sc[hh][t] = s * 0.125f;
    }
    __syncthreads();
    const int hh = tid >> 6, lane = tid & 63;
    float mx = -INFINITY;
    for (int t = lane; t < Tz; t += 64) mx = fmaxf(mx, sc[hh][t]);
    for (int off = 32; off > 0; off >>= 1) mx = fmaxf(mx, __shfl_xor(mx, off));
    float su = 0.f;
    for (int t = lane; t < Tz; t += 64) { float e = expf(sc[hh][t] - mx); sc[hh][t] = e; su += e; }
    for (int off = 32; off > 0; off >>= 1) su += __shfl_xor(su, off);
    float inv = 1.f / su;
    __syncthreads();
    float acc = 0.f;
    #pragma unroll 8
    for (int t = 0; t < Tz; t++) acc += sc[hh][t] * kv[((size_t)b * Tz + t) * 512 + 256 + tid];
    cx[tid] = acc * inv;
    __syncthreads();
    float s2 = 0.f;
    #pragma unroll 8
    for (int i = 0; i < 256; i++) s2 += cx[i] * ca_wo[i * 256 + tid];
    ctx2[b * 256 + tid] = s2 + ca_bo[tid];
}

// ------------- fb = bf16(proj + ctx2) (broadcast over T) ---------------------------------------
__global__ __launch_bounds__(256) void addctx_k(
    const float* __restrict__ proj, const float* __restrict__ ctx2, ushort_t* __restrict__ fb)
{
    size_t idx = (size_t)blockIdx.x * 256 + threadIdx.x;   // over R*E
    int e = (int)(idx & 255);
    int b = (int)(idx >> 17);                              // T*E = 2^17
    fb[idx] = f2bf(proj[idx] + ctx2[b * 256 + e]);
}

// ==============================================================================================
extern "C" void kernel_launch(void* const* d_in, const int* in_sizes, int n_in,
                              void* d_out, int out_size, void* d_ws, size_t ws_size,
                              hipStream_t stream)
{
    const float* x       = (const float*)d_in[0];
    const float* pred_w  = (const float*)d_in[1];
    const float* pred_b  = (const float*)d_in[2];
    const float* t_wqkv  = (const float*)d_in[3];
    const float* t_bqkv  = (const float*)d_in[4];
    const float* t_wo    = (const float*)d_in[5];
    const float* t_bo    = (const float*)d_in[6];
    const float* t_ln1g  = (const float*)d_in[7];
    const float* t_ln1b  = (const float*)d_in[8];
    const float* t_w1    = (const float*)d_in[9];
    const float* t_b1    = (const float*)d_in[10];
    const float* t_w2    = (const float*)d_in[11];
    const float* t_b2    = (const float*)d_in[12];
    const float* t_ln2g  = (const float*)d_in[13];
    const float* t_ln2b  = (const float*)d_in[14];
    const float* sb_w    = (const float*)d_in[15];
    const float* sb_b    = (const float*)d_in[16];
    const float* bn1_g   = (const float*)d_in[17];
    const float* bn1_b   = (const float*)d_in[18];
    const float* bn1_m   = (const float*)d_in[19];
    const float* bn1_v   = (const float*)d_in[20];
    const float* dt_w    = (const float*)d_in[21];
    const float* dt_b    = (const float*)d_in[22];
    const float* cc_w1   = (const float*)d_in[23];
    const float* cc_b1   = (const float*)d_in[24];
    const float* bn2_g   = (const float*)d_in[25];
    const float* bn2_b   = (const float*)d_in[26];
    const float* bn2_m   = (const float*)d_in[27];
    const float* bn2_v   = (const float*)d_in[28];
    const float* cc_w2   = (const float*)d_in[29];
    const float* cc_b2   = (const float*)d_in[30];
    const float* ce      = (const float*)d_in[31];
    const float* kp_w    = (const float*)d_in[32];
    const float* kp_b    = (const float*)d_in[33];
    const float* ca_wqkv = (const float*)d_in[34];
    const float* ca_bqkv = (const float*)d_in[35];
    const float* ca_wo   = (const float*)d_in[36];
    const float* ca_bo   = (const float*)d_in[37];
    const float* fp_w    = (const float*)d_in[38];
    const float* fp_b    = (const float*)d_in[39];
    const float* df_w    = (const float*)d_in[40];
    const float* df_b    = (const float*)d_in[41];

    float* out = (float*)d_out;

    char* wp = (char*)d_ws;
    auto alloc = [&](size_t bytes) -> char* {
        char* r = wp; wp += (bytes + 255) & ~(size_t)255; return r;
    };
    float* scores  = (float*)alloc(BT * 4);
    float* qxbuf   = (float*)alloc((size_t)Bz * Ez * 4);
    float* ctx2buf = (float*)alloc((size_t)Bz * Ez * 4);

    const size_t WT_TOTAL = 2*(size_t)3072*1024 + 2*(size_t)1024*1024 + 2*(size_t)2048*1024
                          + 2*(size_t)1024*2048 + (size_t)512*1024 + (size_t)256*512
                          + 2*(size_t)256*256 + (size_t)1024*256;
    ushort_t* wtb = (ushort_t*)alloc(WT_TOTAL * 2);
    size_t woff = 0;
    auto nxt = [&](size_t n) -> ushort_t* { ushort_t* r = wtb + woff; woff += n; return r; };
    ushort_t* qkvT[2] = { nxt((size_t)3072*1024), nxt((size_t)3072*1024) };
    ushort_t* woT[2]  = { nxt((size_t)1024*1024), nxt((size_t)1024*1024) };
    ushort_t* w1T[2]  = { nxt((size_t)2048*1024), nxt((size_t)2048*1024) };
    ushort_t* w2T[2]  = { nxt((size_t)1024*2048), nxt((size_t)1024*2048) };
    ushort_t* sbT  = nxt((size_t)512*1024);
    ushort_t* kpT  = nxt((size_t)256*512);
    ushort_t* kvT  = nxt((size_t)512*256);
    ushort_t* fpT  = nxt((size_t)1024*256);

    // per-row bytes: hb 2048 + qkvb 6144 + Pb 4096 (r11 layout: R*2048 elems) + Vt 2048 = 14336
    size_t fixedB = (size_t)(wp - (char*)d_ws);
    int Bc = Bz;
    while (Bc > 1 && fixedB + (size_t)Bc * Tz * 14336 + 1048576 > ws_size) Bc >>= 1;
    const int Rmax = Bc * Tz;
    ushort_t* hb   = (ushort_t*)alloc((size_t)Rmax * 1024 * 2);
    ushort_t* qkvb = (ushort_t*)alloc((size_t)Rmax * 3072 * 2);
    ushort_t* Pb   = (ushort_t*)alloc((size_t)Rmax * 2048 * 2);  // r11-size; only first R*1024 used
    ushort_t* Vt   = (ushort_t*)alloc((size_t)Rmax * 1024 * 2);

    // ---- one-time weight transpose+cast: single merged launch ----
    {
        WtJobs J;
        const float* srcs[13] = { t_wqkv, t_wqkv + (size_t)1024*3072, t_wo, t_wo + (size_t)1024*1024,
                                  t_w1, t_w1 + (size_t)1024*2048, t_w2, t_w2 + (size_t)2048*1024,
                                  sb_w, kp_w, ca_wqkv + Ez, ca_wqkv + 2*Ez, fp_w };
        ushort_t* dsts[13] = { qkvT[0], qkvT[1], woT[0], woT[1], w1T[0], w1T[1], w2T[0], w2T[1],
                               sbT, kpT, kvT, kvT + (size_t)256*256, fpT };
        const int lds_[13] = { 3072, 3072, 1024, 1024, 2048, 2048, 1024, 1024, 512, 256, 768, 768, 1024 };
        const int kds_[13] = { 1024, 1024, 1024, 1024, 1024, 1024, 2048, 2048, 1024, 512, 256, 256, 256 };
        const int nxs_[13] = { 96, 96, 32, 32, 64, 64, 32, 32, 16, 8, 8, 8, 32 };
        const int nys_[13] = { 32, 32, 32, 32, 32, 32, 64, 64, 32, 16, 8, 8, 8 };
        int acc = 0;
        for (int i = 0; i < 13; i++) {
            J.src[i] = srcs[i]; J.dst[i] = dsts[i];
            J.ld[i] = lds_[i]; J.Kd[i] = kds_[i]; J.nx[i] = nxs_[i];
            J.base[i] = acc; acc += nxs_[i] * nys_[i];
        }
        J.base[13] = acc;
        wtall_k<<<acc, 256, 0, stream>>>(J);
    }

    for (int b0 = 0; b0 < Bz; b0 += Bc) {
        const int R = Bc * Tz;
        const float* xc = x + (size_t)b0 * Tz * Dz;

        auto MG = [&](const ushort_t* Ain, int lda, const ushort_t* Wt_, const float* bias,
                      float* Cf, ushort_t* Ch, int ldc, int N, int Kd, int epi,
                      const float* g = nullptr, const float* bb = nullptr,
                      const float* m = nullptr, const float* v = nullptr) {
            mgemm_k<<<dim3(N/128, R/128), 256, 0, stream>>>(
                Ain, lda, Wt_, bias, Cf, Ch, ldc, Kd, epi, g, bb, m, v);
        };

        // 1. fused shift-predictor + TSM -> hb
        predshift_k<<<R, 256, 0, stream>>>(xc, pred_w, pred_b, hb);

        // 2. transformer layers
        for (int l = 0; l < Lz; l++) {
            MG(hb, 1024, qkvT[l], t_bqkv + (size_t)l*3072, nullptr, qkvb, 3072, 3072, 1024, 0);
            vtb_k<<<dim3(8, 16, Bc * 4), 256, 0, stream>>>(qkvb, Vt);
            flash_k<<<dim3(4, Bc * 4), 1024, 0, stream>>>(qkvb, Vt);
            MG(qkvb, 3072, woT[l], t_bo + (size_t)l*1024, nullptr, Pb, 1024, 1024, 1024, 0);
            addlnb_k<<<R, 256, 0, stream>>>(hb, Pb,
                                            t_ln1g + (size_t)l*Dz, t_ln1b + (size_t)l*Dz);
            MG(hb, 1024, w1T[l], t_b1 + (size_t)l*FFz, nullptr, qkvb, 2048, 2048, 1024, 1);
            MG(qkvb, 2048, w2T[l], t_b2 + (size_t)l*Dz, nullptr, Pb, 1024, 1024, 2048, 0);
            addlnb_k<<<R, 256, 0, stream>>>(hb, Pb,
                                            t_ln2g + (size_t)l*Dz, t_ln2b + (size_t)l*Dz);
        }

        // ---- tail: fp32 buffers aliased into dead bf16 regions (stream-ordered safe) ----
        float*    shared  = (float*)Vt;                              // [R,512] f32 (Vt dead)
        float*    proj    = (float*)hb;                              // [R,256] f32 (hb dead after sb MG)
        float*    kvb     = (float*)(qkvb + (size_t)R * 1024);       // [R,512] f32
        float*    fin     = (float*)(qkvb + (size_t)R * 2048);       // [R,512] f32
        ushort_t* sharedb = Pb;                                      // [R,512]
        ushort_t* projb   = Pb + (size_t)R * 512;                    // [R,256]
        ushort_t* fb      = Pb + (size_t)R * 768;                    // [R,256]
        ushort_t* fpb     = qkvb;                                    // [R,1024]

        // 3. shared = relu(BN1(h @ sb_w + sb_b))  (dual out)
        MG(hb, 1024, sbT, sb_b, shared, sharedb, 512, 512, 1024, 2, bn1_g, bn1_b, bn1_m, bn1_v);
        // 4. scores (grid=R) + fused topk/agg/classifier (grid=Bc)
        rowdot_k<<<R, 256, 0, stream>>>(shared, dt_w, dt_b, scores + (size_t)b0 * Tz);
        tailcls_k<<<Bc, 256, 0, stream>>>(scores + (size_t)b0 * Tz, shared, cc_w1, cc_b1,
                                          bn2_g, bn2_b, bn2_m, bn2_v, cc_w2, cc_b2,
                                          ce, ca_wqkv, ca_bqkv,
                                          out + BT + (size_t)b0 * KC, qxbuf);
        // 5. proj (dual), combined cross k|v
        MG(sharedb, 512, kpT, kp_b, proj, projb, 256, 256, 512, 0);
        MG(projb, 256, kvT, ca_bqkv + Ez, kvb, nullptr, 512, 512, 256, 0);
        // 6. cross attention (+wo fused) + final fuse
        xattn_k<<<Bc, 256, 0, stream>>>(qxbuf, kvb, ca_wo, ca_bo, ctx2buf);
        addctx_k<<<(R * Ez) / 256, 256, 0, stream>>>(proj, ctx2buf, fb);
        // 7. fp_out (bf16) -> fin (BN+relu fp32) -> seg
        MG(fb, 256, fpT, fp_b, nullptr, fpb, 1024, 1024, 256, 0);
        MG(fpb, 1024, sbT, sb_b, fin, nullptr, 512, 512, 1024, 2, bn1_g, bn1_b, bn1_m, bn1_v);
        rowdot_k<<<R, 256, 0, stream>>>(fin, df_w, df_b, out + (size_t)b0 * Tz);
    }
}

// Round 21
// 1448.106 us; speedup vs baseline: 1.1682x; 1.1682x over previous
//
#include <hip/hip_runtime.h>
#include <math.h>

#define Bz 32
#define Tz 512
#define Dz 1024
#define Pz 512
#define Ez 256
#define KC 14
#define NHz 4
#define Lz 2
#define FFz 2048
#define TOPKz 7
#define EPSz 1e-5f
#define BT (Bz*Tz)

typedef unsigned short ushort_t;
typedef __attribute__((ext_vector_type(8))) short short8;
typedef __attribute__((ext_vector_type(4))) float f32x4;

__device__ __forceinline__ ushort_t f2bf(float f) {
    union { float f; unsigned int u; } x; x.f = f;
    unsigned int r = x.u + 0x7fffu + ((x.u >> 16) & 1u);   // RNE (finite inputs)
    return (ushort_t)(r >> 16);
}
__device__ __forceinline__ float bf2f(ushort_t h) {
    union { unsigned int u; float f; } x; x.u = ((unsigned int)h) << 16; return x.f;
}

#define GLDS(gp, lp) __builtin_amdgcn_global_load_lds( \
    (const __attribute__((address_space(1))) unsigned int*)(gp), \
    (__attribute__((address_space(3))) unsigned int*)(lp), 16, 0, 0)

// ---------------- 128x128 bf16 MFMA GEMM (m97) + serpentine XCD swizzle + staged C-write -------
__global__ __launch_bounds__(256) void mgemm_k(
    const ushort_t* __restrict__ A, int lda,
    const ushort_t* __restrict__ Wt,
    const float* __restrict__ bias,
    float* __restrict__ Cf, ushort_t* __restrict__ Ch, int ldc,
    int Kd, int epi,
    const float* __restrict__ bng, const float* __restrict__ bnb,
    const float* __restrict__ bnm, const float* __restrict__ bnv)
{
    __shared__ __align__(16) ushort_t smem[128 * 136];   // As|Bs (16KB) in loop; C-stage after
    ushort_t* As = smem;
    ushort_t* Bs = smem + 128 * 32;
    const int tid = threadIdx.x;
    const int lane = tid & 63, wid0 = tid >> 6;
    const int gx = gridDim.x;
    const int f = blockIdx.y * gx + blockIdx.x;
    const int chunk = f & 7;
    const int local = f >> 3;                             // 0 .. nwg/8-1
    const int rowsPerChunk = gridDim.y >> 3;              // 16 here
    const int bandSz = 4 * gx;
    const int band = local / bandSz;
    const int rem  = local - band * bandSz;
    const int row0 = (chunk * rowsPerChunk + band * 4 + (rem & 3)) * 128;
    const int col0 = (rem >> 2) * 128;
    const int wrow = (wid0 >> 1) * 64, wcol = (wid0 & 1) * 64;
    const int srow = (lane >> 2);
    const int skoff = (lane & 3) * 8;

    f32x4 acc[4][4];
    const f32x4 zr = {0.f, 0.f, 0.f, 0.f};
    #pragma unroll
    for (int m = 0; m < 4; m++)
        #pragma unroll
        for (int n = 0; n < 4; n++) acc[m][n] = zr;

    for (int k0 = 0; k0 < Kd; k0 += 32) {
        #pragma unroll
        for (int j = 0; j < 2; j++) {
            const int r = wid0 * 32 + j * 16;
            GLDS(A + (size_t)(row0 + r + srow) * lda + k0 + skoff, As + r * 32);
            GLDS(Wt + (size_t)(col0 + r + srow) * Kd + k0 + skoff, Bs + r * 32);
        }
        __syncthreads();
        short8 af[4], bf[4];
        #pragma unroll
        for (int m = 0; m < 4; m++)
            af[m] = *(const short8*)(As + (wrow + m * 16 + (lane & 15)) * 32 + (lane >> 4) * 8);
        #pragma unroll
        for (int n = 0; n < 4; n++)
            bf[n] = *(const short8*)(Bs + (wcol + n * 16 + (lane & 15)) * 32 + (lane >> 4) * 8);
        #pragma unroll
        for (int m = 0; m < 4; m++)
            #pragma unroll
            for (int n = 0; n < 4; n++)
                acc[m][n] = __builtin_amdgcn_mfma_f32_16x16x32_bf16(af[m], bf[n], acc[m][n], 0, 0, 0);
        __syncthreads();
    }

    // ---- epilogue: bias/BN/relu; fp32 scalar (full sectors); bf16 via LDS stage ----
    #pragma unroll
    for (int n = 0; n < 4; n++) {
        const int lcol = wcol + n * 16 + (lane & 15);
        const int ccol = col0 + lcol;
        const float bb = bias[ccol];
        float bsc = 1.f, bsh = 0.f;
        if (epi == 2) {
            bsc = rsqrtf(bnv[ccol] + EPSz) * bng[ccol];
            bsh = bnb[ccol] - bnm[ccol] * bsc;
        }
        #pragma unroll
        for (int m = 0; m < 4; m++) {
            #pragma unroll
            for (int r = 0; r < 4; r++) {
                const int lrow = wrow + m * 16 + (lane >> 4) * 4 + r;
                float y = acc[m][n][r] + bb;
                if (epi == 2) y = y * bsc + bsh;
                if (epi >= 1) y = fmaxf(y, 0.f);
                if (Cf) Cf[(size_t)(row0 + lrow) * ldc + ccol] = y;
                if (Ch) smem[lrow * 136 + lcol] = f2bf(y);
            }
        }
    }
    if (Ch) {
        __syncthreads();
        #pragma unroll
        for (int i = 0; i < 8; i++) {
            const int row = (tid >> 4) + i * 16;
            const int seg = (tid & 15) * 8;
            *(uint4*)(Ch + (size_t)(row0 + row) * ldc + col0 + seg) =
                *(const uint4*)(smem + row * 136 + seg);
        }
    }
}

// ---------------- fused flash attention: S=QK^T -> softmax -> O=PV, P kept in LDS --------------
__global__ __launch_bounds__(1024) void flash_k(
    ushort_t* __restrict__ qkvb, const ushort_t* __restrict__ Vt)
{
    __shared__ __align__(16) ushort_t Plds[128 * 512];   // 128KB; QK staging + O staging overlap
    __shared__ __align__(16) ushort_t Bs2[256 * 32];     // 16KB (PV V^T tiles)
    __shared__ float red[128][4];                        // 2KB
    ushort_t* As = Plds;              // 8KB  (QK phase)
    ushort_t* Bs = Plds + 128 * 32;   // 32KB (QK phase)

    const int z = blockIdx.y, bl = z >> 2, hh = z & 3;
    const int row0 = blockIdx.x * 128;
    ushort_t* Qs = qkvb + (size_t)bl * 512 * 3072 + hh * 256;          // Q (and O dest)
    const ushort_t* Ks = qkvb + (size_t)bl * 512 * 3072 + 1024 + hh * 256;
    const ushort_t* V = Vt + (size_t)z * 256 * 512;
    const int tid = threadIdx.x, lane = tid & 63, w = tid >> 6;
    const int wr = w >> 2, wc = w & 3;                   // 4 x 4

    // ---- phase 1: S = Q K^T ----
    f32x4 acc[2][8];
    const f32x4 zr = {0.f, 0.f, 0.f, 0.f};
    #pragma unroll
    for (int m = 0; m < 2; m++)
        #pragma unroll
        for (int n = 0; n < 8; n++) acc[m][n] = zr;

    for (int d0 = 0; d0 < 256; d0 += 32) {
        if (w < 8) {
            const int rbu = w * 16;
            const int row = rbu + (lane >> 2);
            GLDS(Qs + (size_t)(row0 + row) * 3072 + d0 + (lane & 3) * 8, As + rbu * 32);
        } else {
            #pragma unroll
            for (int i = 0; i < 4; i++) {
                const int rbu = (w - 8) * 64 + i * 16;
                const int row = rbu + (lane >> 2);
                GLDS(Ks + (size_t)row * 3072 + d0 + (lane & 3) * 8, Bs + rbu * 32);
            }
        }
        __syncthreads();
        short8 af[2];
        #pragma unroll
        for (int m = 0; m < 2; m++)
            af[m] = *(const short8*)(As + (wr * 32 + m * 16 + (lane & 15)) * 32 + (lane >> 4) * 8);
        #pragma unroll
        for (int n = 0; n < 8; n++) {
            const short8 bfv = *(const short8*)(Bs + (wc * 128 + n * 16 + (lane & 15)) * 32 + (lane >> 4) * 8);
            #pragma unroll
            for (int m = 0; m < 2; m++)
                acc[m][n] = __builtin_amdgcn_mfma_f32_16x16x32_bf16(af[m], bfv, acc[m][n], 0, 0, 0);
        }
        __syncthreads();
    }

    // ---- phase 2: softmax (scale 1/16) ----
    #pragma unroll
    for (int m = 0; m < 2; m++)
        #pragma unroll
        for (int n = 0; n < 8; n++) acc[m][n] *= 0.0625f;

    float rmx[2][4], rinv[2][4];
    #pragma unroll
    for (int m = 0; m < 2; m++)
        #pragma unroll
        for (int r = 0; r < 4; r++) {
            float mx = acc[m][0][r];
            #pragma unroll
            for (int n = 1; n < 8; n++) mx = fmaxf(mx, acc[m][n][r]);
            mx = fmaxf(mx, __shfl_xor(mx, 1));
            mx = fmaxf(mx, __shfl_xor(mx, 2));
            mx = fmaxf(mx, __shfl_xor(mx, 4));
            mx = fmaxf(mx, __shfl_xor(mx, 8));
            if ((lane & 15) == 0) red[wr * 32 + m * 16 + (lane >> 4) * 4 + r][wc] = mx;
        }
    __syncthreads();
    #pragma unroll
    for (int m = 0; m < 2; m++)
        #pragma unroll
        for (int r = 0; r < 4; r++) {
            const int rw = wr * 32 + m * 16 + (lane >> 4) * 4 + r;
            rmx[m][r] = fmaxf(fmaxf(red[rw][0], red[rw][1]), fmaxf(red[rw][2], red[rw][3]));
        }
    __syncthreads();
    #pragma unroll
    for (int m = 0; m < 2; m++)
        #pragma unroll
        for (int r = 0; r < 4; r++) {
            float s = 0.f;
            #pragma unroll
            for (int n = 0; n < 8; n++) {
                const float e = expf(acc[m][n][r] - rmx[m][r]);
                acc[m][n][r] = e; s += e;
            }
            s += __shfl_xor(s, 1); s += __shfl_xor(s, 2);
            s += __shfl_xor(s, 4); s += __shfl_xor(s, 8);
            if ((lane & 15) == 0) red[wr * 32 + m * 16 + (lane >> 4) * 4 + r][wc] = s;
        }
    __syncthreads();
    #pragma unroll
    for (int m = 0; m < 2; m++)
        #pragma unroll
        for (int r = 0; r < 4; r++) {
            const int rw = wr * 32 + m * 16 + (lane >> 4) * 4 + r;
            rinv[m][r] = 1.f / (red[rw][0] + red[rw][1] + red[rw][2] + red[rw][3]);
        }
    __syncthreads();

    // write normalized P (bf16) into Plds, XOR-swizzled: byte ^= (row&7)<<4
    char* Pc = (char*)Plds;
    #pragma unroll
    for (int m = 0; m < 2; m++)
        #pragma unroll
        for (int r = 0; r < 4; r++) {
            const int rw = wr * 32 + m * 16 + (lane >> 4) * 4 + r;
            const int rx = (rw & 7) << 4;
            #pragma unroll
            for (int n = 0; n < 8; n++) {
                const int col = wc * 128 + n * 16 + (lane & 15);
                *(ushort_t*)(Pc + (((rw * 512 + col) * 2) ^ rx)) = f2bf(acc[m][n][r] * rinv[m][r]);
            }
        }
    __syncthreads();

    // ---- phase 3: O = P @ Vt^T ----
    f32x4 acc2[2][4];
    #pragma unroll
    for (int m = 0; m < 2; m++)
        #pragma unroll
        for (int n = 0; n < 4; n++) acc2[m][n] = zr;

    for (int k0 = 0; k0 < 512; k0 += 32) {
        {
            const int rbu = w * 16;
            const int row = rbu + (lane >> 2);
            GLDS(V + (size_t)row * 512 + k0 + (lane & 3) * 8, Bs2 + rbu * 32);
        }
        __syncthreads();
        short8 af2[2];
        #pragma unroll
        for (int m = 0; m < 2; m++) {
            const int rw = wr * 32 + m * 16 + (lane & 15);
            const int rx = (rw & 7) << 4;
            af2[m] = *(const short8*)(Pc + (((rw * 512 + k0 + (lane >> 4) * 8) * 2) ^ rx));
        }
        #pragma unroll
        for (int n = 0; n < 4; n++) {
            const short8 bfv = *(const short8*)(Bs2 + (wc * 64 + n * 16 + (lane & 15)) * 32 + (lane >> 4) * 8);
            #pragma unroll
            for (int m = 0; m < 2; m++)
                acc2[m][n] = __builtin_amdgcn_mfma_f32_16x16x32_bf16(af2[m], bfv, acc2[m][n], 0, 0, 0);
        }
        __syncthreads();
    }

    // ---- O epilogue: stage bf16 [128][256] into Plds (now free), coalesced uint4 write ----
    #pragma unroll
    for (int n = 0; n < 4; n++) {
        const int ccol = wc * 64 + n * 16 + (lane & 15);
        #pragma unroll
        for (int m = 0; m < 2; m++)
            #pragma unroll
            for (int r = 0; r < 4; r++) {
                const int lrow = wr * 32 + m * 16 + (lane >> 4) * 4 + r;
                Plds[lrow * 256 + ccol] = f2bf(acc2[m][n][r]);
            }
    }
    __syncthreads();
    #pragma unroll
    for (int i = 0; i < 4; i++) {
        const int row = (tid >> 5) + i * 32;
        const int seg = (tid & 31) * 8;
        *(uint4*)(Qs + (size_t)(row0 + row) * 3072 + seg) = *(const uint4*)(Plds + row * 256 + seg);
    }
}

// ------------- z-batched bf16 transpose: V[kv][d] (qkvb v-slots) -> Vt[d][kv] ------------------
__global__ __launch_bounds__(256) void vtb_k(
    const ushort_t* __restrict__ qkvb, ushort_t* __restrict__ Vt)
{
    const int z = blockIdx.z, bl = z >> 2, hh = z & 3;
    const ushort_t* src = qkvb + (size_t)bl * 512 * 3072 + 2048 + hh * 256;
    ushort_t* dst = Vt + (size_t)z * 256 * 512;
    __shared__ ushort_t t[32][33];
    const int tx = threadIdx.x & 31, ty = threadIdx.x >> 5;
    const int gx = blockIdx.x * 32;   // d
    const int gy = blockIdx.y * 32;   // kv
    #pragma unroll
    for (int i = 0; i < 4; i++) {
        const int row = ty + i * 8;
        t[row][tx] = src[(size_t)(gy + row) * 3072 + gx + tx];
    }
    __syncthreads();
    #pragma unroll
    for (int i = 0; i < 4; i++) {
        const int nr = ty + i * 8;
        dst[(size_t)(gx + nr) * 512 + gy + tx] = t[tx][nr];
    }
}

// ------------- merged weight transpose+cast: 13 jobs, one launch -------------------------------
struct WtJobs {
    const float* src[13];
    ushort_t*    dst[13];
    int ld[13];
    int Kd[13];
    int nx[13];
    int base[14];
};

__global__ __launch_bounds__(256) void wtall_k(WtJobs J)
{
    const int bid = blockIdx.x;
    int j = 0;
    #pragma unroll
    for (int i = 0; i < 12; i++) if (bid >= J.base[i + 1]) j = i + 1;
    const int local = bid - J.base[j];
    const int bx = local % J.nx[j], by = local / J.nx[j];
    const float* src = J.src[j];
    ushort_t* dst = J.dst[j];
    const int ld = J.ld[j], Kd = J.Kd[j];

    __shared__ float t[32][33];
    const int tx = threadIdx.x & 31, ty = threadIdx.x >> 5;
    const int gx = bx * 32;
    const int gy = by * 32;
    #pragma unroll
    for (int i = 0; i < 4; i++) {
        const int row = ty + i * 8;
        t[row][tx] = src[(size_t)(gy + row) * ld + gx + tx];
    }
    __syncthreads();
    #pragma unroll
    for (int i = 0; i < 4; i++) {
        const int nr = ty + i * 8;
        dst[(size_t)(gx + nr) * Kd + gy + tx] = f2bf(t[tx][nr]);
    }
}

// ------------- fused shift-predictor + TSM shift (bf16 out) ------------------------------------
__global__ __launch_bounds__(256) void predshift_k(
    const float* __restrict__ x, const float* __restrict__ pred_w,
    const float* __restrict__ pred_b, ushort_t* __restrict__ hb)
{
    const int row = blockIdx.x, tid = threadIdx.x;
    const size_t base = (size_t)row * Dz;
    float s = 0.f;
    #pragma unroll
    for (int i = 0; i < 4; i++) {
        int c = tid + i * 256;
        s += x[base + c] * pred_w[c];
    }
    __shared__ float red[256];
    __shared__ int sns;
    red[tid] = s; __syncthreads();
    for (int off = 128; off > 0; off >>= 1) {
        if (tid < off) red[tid] += red[tid + off];
        __syncthreads();
    }
    if (tid == 0) {
        float sg = 1.f / (1.f + expf(-(red[0] + pred_b[0])));
        sns = (int)(sg * (float)(Dz / 2));
    }
    __syncthreads();
    const int sn = sns;
    const int t = row & (Tz - 1);
    #pragma unroll
    for (int i = 0; i < 4; i++) {
        const int c = tid + i * 256;
        const size_t idx = base + c;
        float v;
        if (c < sn)          v = (t > 0)      ? x[idx - Dz] : 0.f;
        else if (c < 2 * sn) v = (t < Tz - 1) ? x[idx + Dz] : 0.f;
        else                 v = x[idx];
        hb[idx] = f2bf(v);
    }
}

// ------------- hb = bf16(LN(hb + r)) — bf16 residual stream ------------------------------------
__global__ __launch_bounds__(256) void addlnb_k(
    ushort_t* __restrict__ hb, const ushort_t* __restrict__ r,
    const float* __restrict__ g, const float* __restrict__ b)
{
    const int row = blockIdx.x, tid = threadIdx.x;
    const size_t base = (size_t)row * Dz;
    float x[4]; float s = 0.f, sq = 0.f;
    #pragma unroll
    for (int i = 0; i < 4; i++) {
        const int c = tid + i * 256;
        x[i] = bf2f(hb[base + c]) + bf2f(r[base + c]);
        s += x[i]; sq += x[i] * x[i];
    }
    __shared__ float rs[256], rq[256];
    rs[tid] = s; rq[tid] = sq; __syncthreads();
    for (int off = 128; off > 0; off >>= 1) {
        if (tid < off) { rs[tid] += rs[tid + off]; rq[tid] += rq[tid + off]; }
        __syncthreads();
    }
    float mean = rs[0] * (1.f / Dz);
    float var = rq[0] * (1.f / Dz) - mean * mean;
    float inv = rsqrtf(var + EPSz);
    #pragma unroll
    for (int i = 0; i < 4; i++) {
        int c = tid + i * 256;
        float y = (x[i] - mean) * inv * g[c] + b[c];
        hb[base + c] = f2bf(y);
    }
}

// ------------- rowdot: out[row] = dot(in[row,:512], w) + b -------------------------------------
__global__ __launch_bounds__(256) void rowdot_k(
    const float* __restrict__ in, const float* __restrict__ w,
    const float* __restrict__ bptr, float* __restrict__ outf)
{
    const int row = blockIdx.x, tid = threadIdx.x;
    const float* r = in + (size_t)row * Pz;
    float s = 0.f;
    #pragma unroll
    for (int c = tid; c < Pz; c += 256) s += r[c] * w[c];
    __shared__ float red[256];
    red[tid] = s; __syncthreads();
    for (int off = 128; off > 0; off >>= 1) {
        if (tid < off) red[tid] += red[tid + off];
        __syncthreads();
    }
    if (tid == 0) outf[row] = red[0] + bptr[0];
}

// ------------- fused tail: top-k -> agg -> classifier -> logits + cross-q (grid = Bc) ----------
__global__ __launch_bounds__(256) void tailcls_k(
    const float* __restrict__ scores, const float* __restrict__ shared_,
    const float* __restrict__ cc_w1, const float* __restrict__ cc_b1,
    const float* __restrict__ g2, const float* __restrict__ b2,
    const float* __restrict__ m2, const float* __restrict__ v2,
    const float* __restrict__ cc_w2, const float* __restrict__ cc_b2,
    const float* __restrict__ ce,
    const float* __restrict__ ca_wqkv, const float* __restrict__ ca_bqkv,
    float* __restrict__ logits_out, float* __restrict__ qx)
{
    const int b = blockIdx.x, tid = threadIdx.x;
    __shared__ float sv[Tz];
    __shared__ float rv[256]; __shared__ int ri[256];
    __shared__ int tki[TOPKz];
    __shared__ float ag[Pz], c1s[256], sm[16], cemb[256];

    sv[tid] = scores[b * Tz + tid];
    sv[tid + 256] = scores[b * Tz + tid + 256];
    __syncthreads();

    for (int it = 0; it < TOPKz; it++) {
        float v0 = sv[tid]; int i0 = tid;
        float v1 = sv[tid + 256];
        if (v1 > v0) { v0 = v1; i0 = tid + 256; }
        rv[tid] = v0; ri[tid] = i0; __syncthreads();
        for (int off = 128; off > 0; off >>= 1) {
            if (tid < off) {
                if (rv[tid + off] > rv[tid] ||
                    (rv[tid + off] == rv[tid] && ri[tid + off] < ri[tid])) {
                    rv[tid] = rv[tid + off]; ri[tid] = ri[tid + off];
                }
            }
            __syncthreads();
        }
        if (tid == 0) { tki[it] = ri[0]; sv[ri[0]] = -INFINITY; }
        __syncthreads();
    }

    const float* base = shared_ + (size_t)b * Tz * Pz;
    for (int p = tid; p < Pz; p += 256) {
        float s = 0.f;
        #pragma unroll
        for (int j = 0; j < TOPKz; j++) s += base[(size_t)tki[j] * Pz + p];
        ag[p] = s * (1.f / TOPKz);
    }
    __syncthreads();

    float s = 0.f;
    #pragma unroll 8
    for (int p = 0; p < Pz; p++) s += ag[p] * cc_w1[p * 256 + tid];
    s += cc_b1[tid];
    s = (s - m2[tid]) * rsqrtf(v2[tid] + EPSz) * g2[tid] + b2[tid];
    s = fmaxf(s, 0.f);
    c1s[tid] = s;
    __syncthreads();
    if (tid < KC) {
        float l = 0.f;
        #pragma unroll 8
        for (int e = 0; e < 256; e++) l += c1s[e] * cc_w2[e * KC + tid];
        l += cc_b2[tid];
        sm[tid] = l;
        logits_out[b * KC + tid] = l;
    }
    __syncthreads();
    if (tid == 0) {
        float mx = sm[0];
        for (int k = 1; k < KC; k++) mx = fmaxf(mx, sm[k]);
        float su = 0.f;
        for (int k = 0; k < KC; k++) { sm[k] = expf(sm[k] - mx); su += sm[k]; }
        float inv = 1.f / su;
        for (int k = 0; k < KC; k++) sm[k] *= inv;
    }
    __syncthreads();
    float cesum = 0.f;
    #pragma unroll
    for (int k = 0; k < KC; k++) cesum += sm[k] * ce[k * 256 + tid];
    cemb[tid] = cesum; __syncthreads();
    float q = 0.f;
    #pragma unroll 8
    for (int i = 0; i < 256; i++) q += cemb[i] * ca_wqkv[i * 768 + tid];
    qx[b * 256 + tid] = q + ca_bqkv[tid];
}

// ------------- cross-attention (Tq=1) on combined kv[R,512] + fused wo projection --------------
__global__ __launch_bounds__(256) void xattn_k(
    const float* __restrict__ qx, const float* __restrict__ kv,
    const float* __restrict__ ca_wo, const float* __restrict__ ca_bo,
    float* __restrict__ ctx2)
{
    const int b = blockIdx.x, tid = threadIdx.x;
    __shared__ float q4[256];
    __shared__ float sc[NHz][Tz];
    __shared__ float cx[256];
    q4[tid] = qx[b * 256 + tid];
    __syncthreads();
    for (int si = tid; si < NHz * Tz; si += 256) {
        int hh = si >> 9, t = si & (Tz - 1);
        const float* kr = kv + ((size_t)b * Tz + t) * 512 + hh * 64;
        const float* qr = q4 + hh * 64;
        float s = 0.f;
        #pragma unroll 8
        for (int d = 0; d < 64; d++) s += qr[d] * kr[d];
        sc[hh][t] = s * 0.125f;
    }
    __syncthreads();
    const int hh = tid >> 6, lane = tid & 63;
    float mx = -INFINITY;
    for (int t = lane; t < Tz; t += 64) mx = fmaxf(mx, sc[hh][t]);
    for (int off = 32; off > 0; off >>= 1) mx = fmaxf(mx, __shfl_xor(mx, off));
    float su = 0.f;
    for (int t = lane; t < Tz; t += 64) { float e = expf(sc[hh][t] - mx); sc[hh][t] = e; su += e; }
    for (int off = 32; off > 0; off >>= 1) su += __shfl_xor(su, off);
    float inv = 1.f / su;
    __syncthreads();
    float acc = 0.f;
    #pragma unroll 8
    for (int t = 0; t < Tz; t++) acc += sc[hh][t] * kv[((size_t)b * Tz + t) * 512 + 256 + tid];
    cx[tid] = acc * inv;
    __syncthreads();
    float s2 = 0.f;
    #pragma unroll 8
    for (int i = 0; i < 256; i++) s2 += cx[i] * ca_wo[i * 256 + tid];
    ctx2[b * 256 + tid] = s2 + ca_bo[tid];
}

// ------------- fb = bf16(proj + ctx2) (broadcast over T) ---------------------------------------
__global__ __launch_bounds__(256) void addctx_k(
    const float* __restrict__ proj, const float* __restrict__ ctx2, ushort_t* __restrict__ fb)
{
    size_t idx = (size_t)blockIdx.x * 256 + threadIdx.x;   // over R*E
    int e = (int)(idx & 255);
    int b = (int)(idx >> 17);                              // T*E = 2^17
    fb[idx] = f2bf(proj[idx] + ctx2[b * 256 + e]);
}

// ==============================================================================================
extern "C" void kernel_launch(void* const* d_in, const int* in_sizes, int n_in,
                              void* d_out, int out_size, void* d_ws, size_t ws_size,
                              hipStream_t stream)
{
    const float* x       = (const float*)d_in[0];
    const float* pred_w  = (const float*)d_in[1];
    const float* pred_b  = (const float*)d_in[2];
    const float* t_wqkv  = (const float*)d_in[3];
    const float* t_bqkv  = (const float*)d_in[4];
    const float* t_wo    = (const float*)d_in[5];
    const float* t_bo    = (const float*)d_in[6];
    const float* t_ln1g  = (const float*)d_in[7];
    const float* t_ln1b  = (const float*)d_in[8];
    const float* t_w1    = (const float*)d_in[9];
    const float* t_b1    = (const float*)d_in[10];
    const float* t_w2    = (const float*)d_in[11];
    const float* t_b2    = (const float*)d_in[12];
    const float* t_ln2g  = (const float*)d_in[13];
    const float* t_ln2b  = (const float*)d_in[14];
    const float* sb_w    = (const float*)d_in[15];
    const float* sb_b    = (const float*)d_in[16];
    const float* bn1_g   = (const float*)d_in[17];
    const float* bn1_b   = (const float*)d_in[18];
    const float* bn1_m   = (const float*)d_in[19];
    const float* bn1_v   = (const float*)d_in[20];
    const float* dt_w    = (const float*)d_in[21];
    const float* dt_b    = (const float*)d_in[22];
    const float* cc_w1   = (const float*)d_in[23];
    const float* cc_b1   = (const float*)d_in[24];
    const float* bn2_g   = (const float*)d_in[25];
    const float* bn2_b   = (const float*)d_in[26];
    const float* bn2_m   = (const float*)d_in[27];
    const float* bn2_v   = (const float*)d_in[28];
    const float* cc_w2   = (const float*)d_in[29];
    const float* cc_b2   = (const float*)d_in[30];
    const float* ce      = (const float*)d_in[31];
    const float* kp_w    = (const float*)d_in[32];
    const float* kp_b    = (const float*)d_in[33];
    const float* ca_wqkv = (const float*)d_in[34];
    const float* ca_bqkv = (const float*)d_in[35];
    const float* ca_wo   = (const float*)d_in[36];
    const float* ca_bo   = (const float*)d_in[37];
    const float* fp_w    = (const float*)d_in[38];
    const float* fp_b    = (const float*)d_in[39];
    const float* df_w    = (const float*)d_in[40];
    const float* df_b    = (const float*)d_in[41];

    float* out = (float*)d_out;

    char* wp = (char*)d_ws;
    auto alloc = [&](size_t bytes) -> char* {
        char* r = wp; wp += (bytes + 255) & ~(size_t)255; return r;
    };
    float* scores  = (float*)alloc(BT * 4);
    float* qxbuf   = (float*)alloc((size_t)Bz * Ez * 4);
    float* ctx2buf = (float*)alloc((size_t)Bz * Ez * 4);

    const size_t WT_TOTAL = 2*(size_t)3072*1024 + 2*(size_t)1024*1024 + 2*(size_t)2048*1024
                          + 2*(size_t)1024*2048 + (size_t)512*1024 + (size_t)256*512
                          + 2*(size_t)256*256 + (size_t)1024*256;
    ushort_t* wtb = (ushort_t*)alloc(WT_TOTAL * 2);
    size_t woff = 0;
    auto nxt = [&](size_t n) -> ushort_t* { ushort_t* r = wtb + woff; woff += n; return r; };
    ushort_t* qkvT[2] = { nxt((size_t)3072*1024), nxt((size_t)3072*1024) };
    ushort_t* woT[2]  = { nxt((size_t)1024*1024), nxt((size_t)1024*1024) };
    ushort_t* w1T[2]  = { nxt((size_t)2048*1024), nxt((size_t)2048*1024) };
    ushort_t* w2T[2]  = { nxt((size_t)1024*2048), nxt((size_t)1024*2048) };
    ushort_t* sbT  = nxt((size_t)512*1024);
    ushort_t* kpT  = nxt((size_t)256*512);
    ushort_t* kvT  = nxt((size_t)512*256);
    ushort_t* fpT  = nxt((size_t)1024*256);

    // per-row bytes: hb 2048 + qkvb 6144 + Pb 2048 + Vt 2048 = 12288
    size_t fixedB = (size_t)(wp - (char*)d_ws);
    int Bc = Bz;
    while (Bc > 1 && fixedB + (size_t)Bc * Tz * 12288 + 1048576 > ws_size) Bc >>= 1;
    const int Rmax = Bc * Tz;
    ushort_t* hb   = (ushort_t*)alloc((size_t)Rmax * 1024 * 2);
    ushort_t* qkvb = (ushort_t*)alloc((size_t)Rmax * 3072 * 2);
    ushort_t* Pb   = (ushort_t*)alloc((size_t)Rmax * 1024 * 2);
    ushort_t* Vt   = (ushort_t*)alloc((size_t)Rmax * 1024 * 2);

    // ---- one-time weight transpose+cast: single merged launch ----
    {
        WtJobs J;
        const float* srcs[13] = { t_wqkv, t_wqkv + (size_t)1024*3072, t_wo, t_wo + (size_t)1024*1024,
                                  t_w1, t_w1 + (size_t)1024*2048, t_w2, t_w2 + (size_t)2048*1024,
                                  sb_w, kp_w, ca_wqkv + Ez, ca_wqkv + 2*Ez, fp_w };
        ushort_t* dsts[13] = { qkvT[0], qkvT[1], woT[0], woT[1], w1T[0], w1T[1], w2T[0], w2T[1],
                               sbT, kpT, kvT, kvT + (size_t)256*256, fpT };
        const int lds_[13] = { 3072, 3072, 1024, 1024, 2048, 2048, 1024, 1024, 512, 256, 768, 768, 1024 };
        const int kds_[13] = { 1024, 1024, 1024, 1024, 1024, 1024, 2048, 2048, 1024, 512, 256, 256, 256 };
        const int nxs_[13] = { 96, 96, 32, 32, 64, 64, 32, 32, 16, 8, 8, 8, 32 };
        const int nys_[13] = { 32, 32, 32, 32, 32, 32, 64, 64, 32, 16, 8, 8, 8 };
        int acc = 0;
        for (int i = 0; i < 13; i++) {
            J.src[i] = srcs[i]; J.dst[i] = dsts[i];
            J.ld[i] = lds_[i]; J.Kd[i] = kds_[i]; J.nx[i] = nxs_[i];
            J.base[i] = acc; acc += nxs_[i] * nys_[i];
        }
        J.base[13] = acc;
        wtall_k<<<acc, 256, 0, stream>>>(J);
    }

    for (int b0 = 0; b0 < Bz; b0 += Bc) {
        const int R = Bc * Tz;
        const float* xc = x + (size_t)b0 * Tz * Dz;

        auto MG = [&](const ushort_t* Ain, int lda, const ushort_t* Wt_, const float* bias,
                      float* Cf, ushort_t* Ch, int ldc, int N, int Kd, int epi,
                      const float* g = nullptr, const float* bb = nullptr,
                      const float* m = nullptr, const float* v = nullptr) {
            mgemm_k<<<dim3(N/128, R/128), 256, 0, stream>>>(
                Ain, lda, Wt_, bias, Cf, Ch, ldc, Kd, epi, g, bb, m, v);
        };

        // 1. fused shift-predictor + TSM -> hb
        predshift_k<<<R, 256, 0, stream>>>(xc, pred_w, pred_b, hb);

        // 2. transformer layers
        for (int l = 0; l < Lz; l++) {
            MG(hb, 1024, qkvT[l], t_bqkv + (size_t)l*3072, nullptr, qkvb, 3072, 3072, 1024, 0);
            vtb_k<<<dim3(8, 16, Bc * 4), 256, 0, stream>>>(qkvb, Vt);
            flash_k<<<dim3(4, Bc * 4), 1024, 0, stream>>>(qkvb, Vt);
            MG(qkvb, 3072, woT[l], t_bo + (size_t)l*1024, nullptr, Pb, 1024, 1024, 1024, 0);
            addlnb_k<<<R, 256, 0, stream>>>(hb, Pb,
                                            t_ln1g + (size_t)l*Dz, t_ln1b + (size_t)l*Dz);
            MG(hb, 1024, w1T[l], t_b1 + (size_t)l*FFz, nullptr, qkvb, 2048, 2048, 1024, 1);
            MG(qkvb, 2048, w2T[l], t_b2 + (size_t)l*Dz, nullptr, Pb, 1024, 1024, 2048, 0);
            addlnb_k<<<R, 256, 0, stream>>>(hb, Pb,
                                            t_ln2g + (size_t)l*Dz, t_ln2b + (size_t)l*Dz);
        }

        // ---- tail: fp32 buffers aliased into dead bf16 regions (stream-ordered safe) ----
        float*    shared  = (float*)Vt;                              // [R,512] f32 (Vt dead)
        float*    proj    = (float*)hb;                              // [R,256] f32 (hb dead after sb MG)
        float*    kvb     = (float*)(qkvb + (size_t)R * 1024);       // [R,512] f32
        float*    fin     = (float*)(qkvb + (size_t)R * 2048);       // [R,512] f32
        ushort_t* sharedb = Pb;                                      // [R,512]
        ushort_t* projb   = Pb + (size_t)R * 512;                    // [R,256]
        ushort_t* fb      = Pb + (size_t)R * 768;                    // [R,256]
        ushort_t* fpb     = qkvb;                                    // [R,1024]

        // 3. shared = relu(BN1(h @ sb_w + sb_b))  (dual out)
        MG(hb, 1024, sbT, sb_b, shared, sharedb, 512, 512, 1024, 2, bn1_g, bn1_b, bn1_m, bn1_v);
        // 4. scores (grid=R) + fused topk/agg/classifier (grid=Bc)
        rowdot_k<<<R, 256, 0, stream>>>(shared, dt_w, dt_b, scores + (size_t)b0 * Tz);
        tailcls_k<<<Bc, 256, 0, stream>>>(scores + (size_t)b0 * Tz, shared, cc_w1, cc_b1,
                                          bn2_g, bn2_b, bn2_m, bn2_v, cc_w2, cc_b2,
                                          ce, ca_wqkv, ca_bqkv,
                                          out + BT + (size_t)b0 * KC, qxbuf);
        // 5. proj (dual), combined cross k|v
        MG(sharedb, 512, kpT, kp_b, proj, projb, 256, 256, 512, 0);
        MG(projb, 256, kvT, ca_bqkv + Ez, kvb, nullptr, 512, 512, 256, 0);
        // 6. cross attention (+wo fused) + final fuse
        xattn_k<<<Bc, 256, 0, stream>>>(qxbuf, kvb, ca_wo, ca_bo, ctx2buf);
        addctx_k<<<(R * Ez) / 256, 256, 0, stream>>>(proj, ctx2buf, fb);
        // 7. fp_out (bf16) -> fin (BN+relu fp32) -> seg
        MG(fb, 256, fpT, fp_b, nullptr, fpb, 1024, 1024, 256, 0);
        MG(fpb, 1024, sbT, sb_b, fin, nullptr, 512, 512, 1024, 2, bn1_g, bn1_b, bn1_m, bn1_v);
        rowdot_k<<<R, 256, 0, stream>>>(fin, df_w, df_b, out + (size_t)b0 * Tz);
    }
}